// Round 9
// baseline (231.823 us; speedup 1.0000x reference)
//
#include <hip/hip_runtime.h>
#include <hip/hip_bf16.h>
#include <math.h>

#define TOKENS 16384
#define DIM    2048
#define NEXP   16
#define CHUNK  256                 // K-floats per chunk (1 KB per row)
#define NCHUNK (DIM / CHUNK)       // 8
#define TPB    16                  // tokens per block
#define NWAVE  4                   // waves per block (256 thr)

typedef float fvec4 __attribute__((ext_vector_type(4)));

// R9: barrier-free, LDS-free. Per chunk-round the 16 waves/CU (4 blocks x 4
// waves) all read the SAME 16 KB W chunk -> L1-resident after first touch
// (L2-hit). x is streamed with nt loads (evict-first: protects W's L1 lines)
// and prefetched one chunk ahead in registers. acc r[64]=(t,e) per wave over
// its 4 tokens, 64-way k-split. No __syncthreads anywhere -> no vmcnt(0)
// drain events; waves free-run against the HBM stream.
// Epilogue: 6-stage butterfly reduce-scatter + 16-lane top-2 + softmax.
__global__ __launch_bounds__(256, 4) void gating_moe_kernel(
    const float* __restrict__ x,
    const float* __restrict__ noise,
    const float* __restrict__ W,
    const float* __restrict__ b,
    float* __restrict__ out)
{
    const int tid  = threadIdx.x;
    const int lane = tid & 63;
    const int w    = tid >> 6;                   // wave 0..3
    const int block_base = blockIdx.x * TPB;
    const int lane4 = lane * 4;                  // lane's float offset in chunk

    float r[64];
#pragma unroll
    for (int v = 0; v < 64; ++v) r[v] = 0.0f;

    // x row pointers for this wave's 4 tokens (each lane: 16 B granule)
    const float* xr0 = x + (size_t)(block_base + w * 4 + 0) * DIM + lane4;
    const float* xr1 = xr0 + DIM;
    const float* xr2 = xr1 + DIM;
    const float* xr3 = xr2 + DIM;
    const float* wp  = W + lane4;                // expert e row: wp + e*DIM

    // ---- prologue: x chunk 0 into regs (nt) ----
    fvec4 xv0 = __builtin_nontemporal_load((const fvec4*)xr0);
    fvec4 xv1 = __builtin_nontemporal_load((const fvec4*)xr1);
    fvec4 xv2 = __builtin_nontemporal_load((const fvec4*)xr2);
    fvec4 xv3 = __builtin_nontemporal_load((const fvec4*)xr3);

#pragma unroll
    for (int c = 0; c < NCHUNK; ++c) {
        fvec4 xn0, xn1, xn2, xn3;
        if (c + 1 < NCHUNK) {                    // prefetch x chunk c+1
            const int off = (c + 1) * CHUNK;
            xn0 = __builtin_nontemporal_load((const fvec4*)(xr0 + off));
            xn1 = __builtin_nontemporal_load((const fvec4*)(xr1 + off));
            xn2 = __builtin_nontemporal_load((const fvec4*)(xr2 + off));
            xn3 = __builtin_nontemporal_load((const fvec4*)(xr3 + off));
        }

        // ---- compute chunk c: W in 4 batches of 4 experts (L1-hot) ----
        const float* wc = wp + c * CHUNK;
#pragma unroll
        for (int eb = 0; eb < NEXP; eb += 4) {
            fvec4 wv0 = *(const fvec4*)(wc + (size_t)(eb + 0) * DIM);
            fvec4 wv1 = *(const fvec4*)(wc + (size_t)(eb + 1) * DIM);
            fvec4 wv2 = *(const fvec4*)(wc + (size_t)(eb + 2) * DIM);
            fvec4 wv3 = *(const fvec4*)(wc + (size_t)(eb + 3) * DIM);
#define FMA4(acc, xv, wv) acc = fmaf((xv).x,(wv).x, fmaf((xv).y,(wv).y, \
                                fmaf((xv).z,(wv).z, fmaf((xv).w,(wv).w,(acc)))))
            FMA4(r[0*16+eb+0], xv0, wv0); FMA4(r[1*16+eb+0], xv1, wv0);
            FMA4(r[2*16+eb+0], xv2, wv0); FMA4(r[3*16+eb+0], xv3, wv0);
            FMA4(r[0*16+eb+1], xv0, wv1); FMA4(r[1*16+eb+1], xv1, wv1);
            FMA4(r[2*16+eb+1], xv2, wv1); FMA4(r[3*16+eb+1], xv3, wv1);
            FMA4(r[0*16+eb+2], xv0, wv2); FMA4(r[1*16+eb+2], xv1, wv2);
            FMA4(r[2*16+eb+2], xv2, wv2); FMA4(r[3*16+eb+2], xv3, wv2);
            FMA4(r[0*16+eb+3], xv0, wv3); FMA4(r[1*16+eb+3], xv1, wv3);
            FMA4(r[2*16+eb+3], xv2, wv3); FMA4(r[3*16+eb+3], xv3, wv3);
#undef FMA4
        }
        if (c + 1 < NCHUNK) { xv0 = xn0; xv1 = xn1; xv2 = xn2; xv3 = xn3; }
    }

    // ---- butterfly reduce-scatter over 64 lanes: after stage s, r[i]
    // holds the partial for value v = (i << (s+1)) + (lane & ((2<<s)-1)).
    // Final: lane L holds the full sum for v = L = t*16 + e. ----
#pragma unroll
    for (int s = 0; s < 6; ++s) {
        const int dist = 1 << s;
        const bool bsel = (lane >> s) & 1;
        const int n = 64 >> (s + 1);
#pragma unroll
        for (int i = 0; i < n; ++i) {
            float keep = bsel ? r[2 * i + 1] : r[2 * i];
            float send = bsel ? r[2 * i]     : r[2 * i + 1];
            r[i] = keep + __shfl_xor(send, dist);
        }
    }

    // ---- epilogue: lane L -> (t = L>>4, e = L&15) of this wave ----
    const int e = lane & 15;
    const size_t obase = (size_t)block_base * NEXP + (size_t)w * 64;
    float nz    = noise[obase + lane];          // noise[t][e], coalesced
    float noisy = r[0] + b[e] + 0.1f * nz;

    // Top-2 across the 16 lanes of the token group (xor 1,2,4,8 stays inside).
    float v1 = noisy; int i1 = e;
    float v2 = -INFINITY; int i2 = 999;
#pragma unroll
    for (int s = 0; s < 4; ++s) {
        const int d = 1 << s;
        float ov1 = __shfl_xor(v1, d); int oi1 = __shfl_xor(i1, d);
        float ov2 = __shfl_xor(v2, d); int oi2 = __shfl_xor(i2, d);
        bool awin = (v1 > ov1) || (v1 == ov1 && i1 < oi1);
        float t1v = awin ? v1  : ov1;  int t1i = awin ? i1  : oi1;
        float lv  = awin ? ov1 : v1;   int li  = awin ? oi1 : i1;
        float cv  = awin ? v2  : ov2;  int ci  = awin ? i2  : oi2;
        bool bwin = (cv > lv) || (cv == lv && ci < li);
        v1 = t1v; i1 = t1i;
        v2 = bwin ? cv : lv; i2 = bwin ? ci : li;
    }

    float dd = __expf(v2 - v1);
    float w1 = 1.0f / (1.0f + dd);
    float w2 = dd * w1;

    float o = (e == i1) ? w1 : ((e == i2) ? w2 : 0.0f);
    out[obase + lane] = o;   // out[t*16 + e], 256B contiguous per wave
}

extern "C" void kernel_launch(void* const* d_in, const int* in_sizes, int n_in,
                              void* d_out, int out_size, void* d_ws, size_t ws_size,
                              hipStream_t stream) {
    const float* x     = (const float*)d_in[0];
    const float* noise = (const float*)d_in[1];
    const float* W     = (const float*)d_in[2];
    const float* b     = (const float*)d_in[3];
    float* out = (float*)d_out;

    dim3 grid(TOKENS / TPB);   // 1024 blocks
    dim3 block(NWAVE * 64);    // 256 threads
    gating_moe_kernel<<<grid, block, 0, stream>>>(x, noise, W, b, out);
}